// Round 1
// baseline (168.043 us; speedup 1.0000x reference)
//
#include <hip/hip_runtime.h>

#define NTOK 2048
#define SCALE 0.125f

typedef unsigned short ushort_t;
typedef unsigned short ushortx8 __attribute__((ext_vector_type(8)));
typedef unsigned short ushortx4 __attribute__((ext_vector_type(4)));
typedef short bf16x8 __attribute__((ext_vector_type(8)));
typedef float f32x4 __attribute__((ext_vector_type(4)));

__device__ inline ushort_t f2bf(float f) {
  unsigned int u = __float_as_uint(f);
  u += 0x7FFFu + ((u >> 16) & 1u);
  return (ushort_t)(u >> 16);
}
__device__ inline float bf2f(ushort_t u) {
  return __uint_as_float(((unsigned int)u) << 16);
}

// ---------------- fp32 -> bf16 elementwise ----------------
__global__ __launch_bounds__(256) void cvt_kernel(const float* __restrict__ src,
                                                  ushort_t* __restrict__ dst, int n) {
  int idx = (blockIdx.x * 256 + threadIdx.x) * 4;
  if (idx >= n) return;
  float4 f = *(const float4*)(src + idx);
  ushortx4 o = { f2bf(f.x), f2bf(f.y), f2bf(f.z), f2bf(f.w) };
  *(ushortx4*)(dst + idx) = o;
}

// ---------------- transpose fp32 [1024][C] -> bf16 dst[row_off + c][k] ----------------
__global__ __launch_bounds__(256) void transpose_cvt_kernel(const float* __restrict__ src, int C,
                                                            ushort_t* __restrict__ dst, int row_off) {
  __shared__ float t[64][65];
  const int c0 = blockIdx.x * 64;
  const int k0 = blockIdx.y * 64;
  const int tid = threadIdx.x;
  const int c = tid & 63, r4 = tid >> 6;
  for (int rr = r4; rr < 64; rr += 4)
    t[c][rr] = src[(size_t)(k0 + rr) * C + c0 + c];
  __syncthreads();
  const int kk = tid & 63, n4 = tid >> 6;
  for (int nn = n4; nn < 64; nn += 4)
    dst[(size_t)(row_off + c0 + nn) * 1024 + k0 + kk] = f2bf(t[nn][kk]);
}

// ---------------- bf16 GEMM, m97 structure: C[M][N] = A[M][K] * Bt[N][K]^T ----------------
// mode 0: split write to q/k/v bf16 buffers (N=1536). mode 1: fp32 out (N=Nout).
__global__ __launch_bounds__(256) void gemm_bf16_kernel(
    const ushort_t* __restrict__ A, const ushort_t* __restrict__ Bt, int K, int mode,
    ushort_t* __restrict__ qout, ushort_t* __restrict__ kout, ushort_t* __restrict__ vout,
    float* __restrict__ fout, int Nout)
{
  __shared__ __align__(16) ushort_t lA[128 * 32];
  __shared__ __align__(16) ushort_t lB[128 * 32];
  const int tid = threadIdx.x;
  const int lane = tid & 63;
  const int quad = lane >> 4;
  const int l16 = lane & 15;
  const int wid = tid >> 6;
  const int rw = (wid >> 1) * 64, cw = (wid & 1) * 64;
  const int m0 = blockIdx.y * 128, n0 = blockIdx.x * 128;

  // staging: 256 threads x 16B x 2 rounds per 8KB tile; LDS offset = tid*16 + round*4096
  const int e0 = tid * 8;              // ushort elements
  const int r0 = e0 >> 5, c0 = e0 & 31;
  const int e1 = e0 + 2048;
  const int r1 = e1 >> 5, c1 = e1 & 31;

  const ushort_t* Ab = A + (size_t)m0 * K;
  const ushort_t* Bb = Bt + (size_t)n0 * K;

  f32x4 acc[4][4] = {};

  for (int k0 = 0; k0 < K; k0 += 32) {
    __syncthreads();
    __builtin_amdgcn_global_load_lds(
        (const __attribute__((address_space(1))) unsigned int*)(Ab + (size_t)r0 * K + k0 + c0),
        (__attribute__((address_space(3))) unsigned int*)(lA + e0), 16, 0, 0);
    __builtin_amdgcn_global_load_lds(
        (const __attribute__((address_space(1))) unsigned int*)(Ab + (size_t)r1 * K + k0 + c1),
        (__attribute__((address_space(3))) unsigned int*)(lA + e1), 16, 0, 0);
    __builtin_amdgcn_global_load_lds(
        (const __attribute__((address_space(1))) unsigned int*)(Bb + (size_t)r0 * K + k0 + c0),
        (__attribute__((address_space(3))) unsigned int*)(lB + e0), 16, 0, 0);
    __builtin_amdgcn_global_load_lds(
        (const __attribute__((address_space(1))) unsigned int*)(Bb + (size_t)r1 * K + k0 + c1),
        (__attribute__((address_space(3))) unsigned int*)(lB + e1), 16, 0, 0);
    __syncthreads();

    bf16x8 bfr[4];
#pragma unroll
    for (int ni = 0; ni < 4; ++ni)
      bfr[ni] = *(const bf16x8*)(lB + (cw + ni * 16 + l16) * 32 + quad * 8);
#pragma unroll
    for (int mi = 0; mi < 4; ++mi) {
      bf16x8 afr = *(const bf16x8*)(lA + (rw + mi * 16 + l16) * 32 + quad * 8);
#pragma unroll
      for (int ni = 0; ni < 4; ++ni)
        acc[mi][ni] = __builtin_amdgcn_mfma_f32_16x16x32_bf16(afr, bfr[ni], acc[mi][ni], 0, 0, 0);
    }
  }

  // epilogue: D row = quad*4+r, col = l16 (verified m89/m91 layout)
#pragma unroll
  for (int mi = 0; mi < 4; ++mi) {
#pragma unroll
    for (int ni = 0; ni < 4; ++ni) {
#pragma unroll
      for (int r = 0; r < 4; ++r) {
        int row = m0 + rw + mi * 16 + quad * 4 + r;
        int col = n0 + cw + ni * 16 + l16;
        float v = acc[mi][ni][r];
        if (mode == 0) {
          if (col < 1024)      qout[(size_t)row * 1024 + col] = f2bf(v);
          else if (col < 1280) kout[(size_t)row * 256 + (col - 1024)] = f2bf(v);
          else                 vout[(size_t)row * 256 + (col - 1280)] = f2bf(v);
        } else {
          fout[(size_t)row * Nout + col] = v;
        }
      }
    }
  }
}

// ---------------- attention: one block per (head, 64-query tile) ----------------
__global__ __launch_bounds__(256) void attn_kernel(
    const ushort_t* __restrict__ Q, const ushort_t* __restrict__ Kb,
    const ushort_t* __restrict__ Vb, ushort_t* __restrict__ O)
{
  __shared__ __align__(16) ushort_t lK[128 * 64];
  __shared__ __align__(16) ushort_t lV[128 * 64];
  __shared__ __align__(16) ushort_t lKg[32 * 64];
  __shared__ __align__(16) ushort_t lVg[32 * 64];
  __shared__ __align__(16) ushort_t lP[64 * 160];
  __shared__ float lInv[64 * 2];

  const int h = blockIdx.x;     // 16
  const int qb = blockIdx.y;    // 32
  const int tid = threadIdx.x;
  const int kvcol = (h >> 2) * 64;   // kv head = h/4 (repeat=4)
  const int kbase = qb * 64 - 64;    // key pos of local slot j=0

  // stage local K/V (128 rows; rows with kpos<0 zeroed) and global K/V (32 rows)
  for (int idx = tid; idx < 1024; idx += 256) {
    int row = idx >> 3, c8 = (idx & 7) * 8;
    int kpos = kbase + row;
    ushortx8 kv = {0,0,0,0,0,0,0,0}, vv = {0,0,0,0,0,0,0,0};
    if (kpos >= 0) {
      kv = *(const ushortx8*)(Kb + (size_t)kpos * 256 + kvcol + c8);
      vv = *(const ushortx8*)(Vb + (size_t)kpos * 256 + kvcol + c8);
    }
    *(ushortx8*)(lK + row * 64 + c8) = kv;
    *(ushortx8*)(lV + row * 64 + c8) = vv;
  }
  {
    int row = tid >> 3, c8 = (tid & 7) * 8;   // exactly 256 chunks
    int kpos = row * 64;
    *(ushortx8*)(lKg + row * 64 + c8) = *(const ushortx8*)(Kb + (size_t)kpos * 256 + kvcol + c8);
    *(ushortx8*)(lVg + row * 64 + c8) = *(const ushortx8*)(Vb + (size_t)kpos * 256 + kvcol + c8);
  }

  const int i = tid >> 2, sub = tid & 3;   // 4 threads per query row
  const int qpos = qb * 64 + i;

  float qf[64];
  {
    const ushort_t* qrow = Q + (size_t)qpos * 1024 + h * 64;
#pragma unroll
    for (int c = 0; c < 64; c += 8) {
      ushortx8 u = *(const ushortx8*)(qrow + c);
#pragma unroll
      for (int e = 0; e < 8; ++e) qf[c + e] = bf2f(u[e]);
    }
  }
  const float slope = exp2f(-0.5f * (float)(h + 1));
  __syncthreads();

  // ---- local scores: valid keys are j = i..i+64 (65 of them); this thread: jo = sub+4t ----
  float sl[17];
#pragma unroll
  for (int t = 0; t < 17; ++t) {
    int jo = sub + 4 * t;
    int j = i + jo;
    int jr = j < 127 ? j : 127;            // clamp for safe LDS read
    bool ok = (jo <= 64) && (kbase + j >= 0);
    float s = 0.f;
    const ushort_t* krow = lK + jr * 64;
#pragma unroll
    for (int c = 0; c < 64; c += 8) {
      ushortx8 u = *(const ushortx8*)(krow + c);
      s += qf[c+0]*bf2f(u[0]) + qf[c+1]*bf2f(u[1]) + qf[c+2]*bf2f(u[2]) + qf[c+3]*bf2f(u[3])
         + qf[c+4]*bf2f(u[4]) + qf[c+5]*bf2f(u[5]) + qf[c+6]*bf2f(u[6]) + qf[c+7]*bf2f(u[7]);
    }
    float dist = (float)((kbase + j) - qpos);   // <= 0 when valid
    s = s * SCALE + dist * slope;
    sl[t] = ok ? s : -1e30f;
  }
  float m = -1e30f;
#pragma unroll
  for (int t = 0; t < 17; ++t) m = fmaxf(m, sl[t]);
  m = fmaxf(m, __shfl_xor(m, 1));
  m = fmaxf(m, __shfl_xor(m, 2));
  float l = 0.f;
#pragma unroll
  for (int t = 0; t < 17; ++t) { float p = __expf(sl[t] - m); sl[t] = p; l += p; }
  l += __shfl_xor(l, 1);
  l += __shfl_xor(l, 2);
#pragma unroll
  for (int t = 0; t < 17; ++t) {
    int jo = sub + 4 * t;
    if (jo <= 64) lP[i * 160 + (i + jo)] = f2bf(sl[t]);
  }
  if (sub == 0) lInv[i * 2 + 0] = 1.f / l;

  // ---- global scores: 32 strided keys, no mask, no alibi ----
  float sg[8];
#pragma unroll
  for (int t = 0; t < 8; ++t) {
    int g = sub + 4 * t;
    float s = 0.f;
    const ushort_t* krow = lKg + g * 64;
#pragma unroll
    for (int c = 0; c < 64; c += 8) {
      ushortx8 u = *(const ushortx8*)(krow + c);
      s += qf[c+0]*bf2f(u[0]) + qf[c+1]*bf2f(u[1]) + qf[c+2]*bf2f(u[2]) + qf[c+3]*bf2f(u[3])
         + qf[c+4]*bf2f(u[4]) + qf[c+5]*bf2f(u[5]) + qf[c+6]*bf2f(u[6]) + qf[c+7]*bf2f(u[7]);
    }
    sg[t] = s * SCALE;
  }
  float mg = -1e30f;
#pragma unroll
  for (int t = 0; t < 8; ++t) mg = fmaxf(mg, sg[t]);
  mg = fmaxf(mg, __shfl_xor(mg, 1));
  mg = fmaxf(mg, __shfl_xor(mg, 2));
  float lg = 0.f;
#pragma unroll
  for (int t = 0; t < 8; ++t) { float p = __expf(sg[t] - mg); sg[t] = p; lg += p; }
  lg += __shfl_xor(lg, 1);
  lg += __shfl_xor(lg, 2);
#pragma unroll
  for (int t = 0; t < 8; ++t) lP[i * 160 + 128 + sub + 4 * t] = f2bf(sg[t]);
  if (sub == 0) lInv[i * 2 + 1] = 1.f / lg;

  __syncthreads();

  // ---- PV: thread -> (query i, 16-dim chunk) ----
  const int dc = sub * 16;
  float accL[16] = {};
  float accG[16] = {};
  const ushort_t* prow = lP + i * 160;
  for (int jo = 0; jo <= 64; ++jo) {
    int j = i + jo;
    float p = bf2f(prow[j]);
    const ushort_t* vrow = lV + j * 64 + dc;
#pragma unroll
    for (int c = 0; c < 16; c += 8) {
      ushortx8 u = *(const ushortx8*)(vrow + c);
#pragma unroll
      for (int e = 0; e < 8; ++e) accL[c + e] += p * bf2f(u[e]);
    }
  }
  for (int g = 0; g < 32; ++g) {
    float p = bf2f(prow[128 + g]);
    const ushort_t* vrow = lVg + g * 64 + dc;
#pragma unroll
    for (int c = 0; c < 16; c += 8) {
      ushortx8 u = *(const ushortx8*)(vrow + c);
#pragma unroll
      for (int e = 0; e < 8; ++e) accG[c + e] += p * bf2f(u[e]);
    }
  }
  const float invL = lInv[i * 2 + 0], invG = lInv[i * 2 + 1];
  ushortx8 o0, o1;
#pragma unroll
  for (int e = 0; e < 8; ++e) o0[e] = f2bf(invL * accL[e] + invG * accG[e]);
#pragma unroll
  for (int e = 0; e < 8; ++e) o1[e] = f2bf(invL * accL[8 + e] + invG * accG[8 + e]);
  ushort_t* orow = O + (size_t)qpos * 1024 + h * 64 + dc;
  *(ushortx8*)(orow) = o0;
  *(ushortx8*)(orow + 8) = o1;
}

extern "C" void kernel_launch(void* const* d_in, const int* in_sizes, int n_in,
                              void* d_out, int out_size, void* d_ws, size_t ws_size,
                              hipStream_t stream)
{
  const float* x  = (const float*)d_in[0];
  const float* Wq = (const float*)d_in[1];
  const float* Wk = (const float*)d_in[2];
  const float* Wv = (const float*)d_in[3];
  const float* Wo = (const float*)d_in[4];
  float* out = (float*)d_out;

  char* ws = (char*)d_ws;
  ushort_t* x_bf   = (ushort_t*)(ws);                        // 4 MB   [2048][1024]
  ushort_t* wqkv_t = (ushort_t*)(ws + (4ull  << 20));        // 3 MB   [1536][1024]
  ushort_t* wo_t   = (ushort_t*)(ws + (7ull  << 20));        // 2 MB   [1024][1024]
  ushort_t* q_bf   = (ushort_t*)(ws + (9ull  << 20));        // 4 MB   [2048][1024]
  ushort_t* k_bf   = (ushort_t*)(ws + (13ull << 20));        // 1 MB   [2048][256]
  ushort_t* v_bf   = (ushort_t*)(ws + (14ull << 20));        // 1 MB   [2048][256]
  ushort_t* at_bf  = (ushort_t*)(ws + (15ull << 20));        // 4 MB   [2048][1024]

  cvt_kernel<<<2048, 256, 0, stream>>>(x, x_bf, 2048 * 1024);
  transpose_cvt_kernel<<<dim3(16, 16), 256, 0, stream>>>(Wq, 1024, wqkv_t, 0);
  transpose_cvt_kernel<<<dim3(4, 16),  256, 0, stream>>>(Wk, 256,  wqkv_t, 1024);
  transpose_cvt_kernel<<<dim3(4, 16),  256, 0, stream>>>(Wv, 256,  wqkv_t, 1280);
  transpose_cvt_kernel<<<dim3(16, 16), 256, 0, stream>>>(Wo, 1024, wo_t, 0);

  gemm_bf16_kernel<<<dim3(12, 16), 256, 0, stream>>>(x_bf, wqkv_t, 1024, 0,
                                                     q_bf, k_bf, v_bf, nullptr, 0);
  attn_kernel<<<dim3(16, 32), 256, 0, stream>>>(q_bf, k_bf, v_bf, at_bf);
  gemm_bf16_kernel<<<dim3(8, 16), 256, 0, stream>>>(at_bf, wo_t, 1024, 1,
                                                    nullptr, nullptr, nullptr, out, 1024);
}

// Round 2
// 125.643 us; speedup vs baseline: 1.3375x; 1.3375x over previous
//
#include <hip/hip_runtime.h>

#define SCALE 0.125f

typedef unsigned short ushort_t;
typedef unsigned short ushortx8 __attribute__((ext_vector_type(8)));
typedef unsigned short ushortx4 __attribute__((ext_vector_type(4)));
typedef short bf16x8 __attribute__((ext_vector_type(8)));
typedef float f32x4 __attribute__((ext_vector_type(4)));

__device__ inline ushort_t f2bf(float f) {
  unsigned int u = __float_as_uint(f);
  u += 0x7FFFu + ((u >> 16) & 1u);
  return (ushort_t)(u >> 16);
}
__device__ inline float bf2f(ushort_t u) {
  return __uint_as_float(((unsigned int)u) << 16);
}

// ---------------- fused prep: x cvt + 4 weight transposes ----------------
// blocks 0..2047: cvt x (2M elements, 4/thread)
// blocks 2048..2303: Wq^T  2304..2367: Wk^T  2368..2431: Wv^T  2432..2687: Wo^T
__global__ __launch_bounds__(256) void prep_kernel(
    const float* __restrict__ x, const float* __restrict__ Wq, const float* __restrict__ Wk,
    const float* __restrict__ Wv, const float* __restrict__ Wo,
    ushort_t* __restrict__ x_bf, ushort_t* __restrict__ wqkv_t, ushort_t* __restrict__ wo_t)
{
  __shared__ float t[64][65];
  int bid = blockIdx.x;
  const int tid = threadIdx.x;
  if (bid < 2048) {
    int idx = (bid * 256 + tid) * 4;
    if (idx < 2048 * 1024) {
      float4 f = *(const float4*)(x + idx);
      ushortx4 o = { f2bf(f.x), f2bf(f.y), f2bf(f.z), f2bf(f.w) };
      *(ushortx4*)(x_bf + idx) = o;
    }
    return;
  }
  bid -= 2048;
  const float* src; int C; ushort_t* dst; int row_off, cb, kb;
  if (bid < 256)      { src = Wq; C = 1024; dst = wqkv_t; row_off = 0;    cb = bid & 15; kb = bid >> 4; }
  else if (bid < 320) { int j = bid - 256; src = Wk; C = 256; dst = wqkv_t; row_off = 1024; cb = j & 3; kb = j >> 2; }
  else if (bid < 384) { int j = bid - 320; src = Wv; C = 256; dst = wqkv_t; row_off = 1280; cb = j & 3; kb = j >> 2; }
  else                { int j = bid - 384; src = Wo; C = 1024; dst = wo_t; row_off = 0;    cb = j & 15; kb = j >> 4; }
  const int c0 = cb * 64, k0 = kb * 64;
  const int c = tid & 63, r4 = tid >> 6;
  for (int rr = r4; rr < 64; rr += 4)
    t[c][rr] = src[(size_t)(k0 + rr) * C + c0 + c];
  __syncthreads();
  const int kk = tid & 63, n4 = tid >> 6;
  for (int nn = n4; nn < 64; nn += 4)
    dst[(size_t)(row_off + c0 + nn) * 1024 + k0 + kk] = f2bf(t[nn][kk]);
}

// ---------------- QKV GEMM (m97 structure): C = A[2048][1024] * Bt[1536][1024]^T ----------------
__global__ __launch_bounds__(256) void gemm_qkv_kernel(
    const ushort_t* __restrict__ A, const ushort_t* __restrict__ Bt,
    ushort_t* __restrict__ qout, ushort_t* __restrict__ kout, ushort_t* __restrict__ vout)
{
  __shared__ __align__(16) ushort_t lA[128 * 32];
  __shared__ __align__(16) ushort_t lB[128 * 32];
  const int tid = threadIdx.x;
  const int lane = tid & 63;
  const int quad = lane >> 4;
  const int l16 = lane & 15;
  const int wid = tid >> 6;
  const int rw = (wid >> 1) * 64, cw = (wid & 1) * 64;
  const int m0 = blockIdx.y * 128, n0 = blockIdx.x * 128;

  const int e0 = tid * 8;
  const int r0 = e0 >> 5, c0 = e0 & 31;
  const int e1 = e0 + 2048;
  const int r1 = e1 >> 5, c1 = e1 & 31;

  const ushort_t* Ab = A + (size_t)m0 * 1024;
  const ushort_t* Bb = Bt + (size_t)n0 * 1024;

  f32x4 acc[4][4] = {};

  for (int k0 = 0; k0 < 1024; k0 += 32) {
    __syncthreads();
    __builtin_amdgcn_global_load_lds(
        (const __attribute__((address_space(1))) unsigned int*)(Ab + (size_t)r0 * 1024 + k0 + c0),
        (__attribute__((address_space(3))) unsigned int*)(lA + e0), 16, 0, 0);
    __builtin_amdgcn_global_load_lds(
        (const __attribute__((address_space(1))) unsigned int*)(Ab + (size_t)r1 * 1024 + k0 + c1),
        (__attribute__((address_space(3))) unsigned int*)(lA + e1), 16, 0, 0);
    __builtin_amdgcn_global_load_lds(
        (const __attribute__((address_space(1))) unsigned int*)(Bb + (size_t)r0 * 1024 + k0 + c0),
        (__attribute__((address_space(3))) unsigned int*)(lB + e0), 16, 0, 0);
    __builtin_amdgcn_global_load_lds(
        (const __attribute__((address_space(1))) unsigned int*)(Bb + (size_t)r1 * 1024 + k0 + c1),
        (__attribute__((address_space(3))) unsigned int*)(lB + e1), 16, 0, 0);
    __syncthreads();

    bf16x8 bfr[4];
#pragma unroll
    for (int ni = 0; ni < 4; ++ni)
      bfr[ni] = *(const bf16x8*)(lB + (cw + ni * 16 + l16) * 32 + quad * 8);
#pragma unroll
    for (int mi = 0; mi < 4; ++mi) {
      bf16x8 afr = *(const bf16x8*)(lA + (rw + mi * 16 + l16) * 32 + quad * 8);
#pragma unroll
      for (int ni = 0; ni < 4; ++ni)
        acc[mi][ni] = __builtin_amdgcn_mfma_f32_16x16x32_bf16(afr, bfr[ni], acc[mi][ni], 0, 0, 0);
    }
  }

#pragma unroll
  for (int mi = 0; mi < 4; ++mi) {
#pragma unroll
    for (int ni = 0; ni < 4; ++ni) {
#pragma unroll
      for (int r = 0; r < 4; ++r) {
        int row = m0 + rw + mi * 16 + quad * 4 + r;
        int col = n0 + cw + ni * 16 + l16;
        float v = acc[mi][ni][r];
        if (col < 1024)      qout[(size_t)row * 1024 + col] = f2bf(v);
        else if (col < 1280) kout[(size_t)row * 256 + (col - 1024)] = f2bf(v);
        else                 vout[(size_t)row * 256 + (col - 1280)] = f2bf(v);
      }
    }
  }
}

// ---------------- MFMA attention: block = (head, 64-query tile) ----------------
// lK  [128 key][64 dim], xor-swizzled 16B chunks  (16 KB)
// lVt [64 dim][128 key], xor-swizzled              (16 KB)
// lKg [32 gkey][64 dim], xor-swizzled              ( 4 KB)
// lVtg[64 dim][32 gkey], stride 40                 ( 5 KB)
// lP  [64 q][128 key],  xor-swizzled (wave-private rows, no barrier) (16 KB)
// lPg [64 q][32 gkey],  stride 40                  ( 5 KB)   total 62 KB -> 2 blocks/CU
__global__ __launch_bounds__(256) void attn_mfma_kernel(
    const ushort_t* __restrict__ Q, const ushort_t* __restrict__ Kb,
    const ushort_t* __restrict__ Vb, ushort_t* __restrict__ O)
{
  __shared__ __align__(16) ushort_t lK[128 * 64];
  __shared__ __align__(16) ushort_t lVt[64 * 128];
  __shared__ __align__(16) ushort_t lKg[32 * 64];
  __shared__ __align__(16) ushort_t lVtg[64 * 40];
  __shared__ __align__(16) ushort_t lP[64 * 128];
  __shared__ __align__(16) ushort_t lPg[64 * 40];

  const int h = blockIdx.x, qb = blockIdx.y;
  const int tid = threadIdx.x;
  const int kvcol = (h >> 2) * 64;
  const int kbase = qb * 64 - 64;

  // ---- stage local K and V^T ----
  for (int cidx = tid; cidx < 1024; cidx += 256) {
    const int key = cidx >> 3, ch = cidx & 7;
    const int kpos = kbase + key;
    ushortx8 kv = {0,0,0,0,0,0,0,0}, vv = {0,0,0,0,0,0,0,0};
    if (kpos >= 0) {
      kv = *(const ushortx8*)(Kb + (size_t)kpos * 256 + kvcol + ch * 8);
      vv = *(const ushortx8*)(Vb + (size_t)kpos * 256 + kvcol + ch * 8);
    }
    *(ushortx8*)(lK + key * 64 + ((ch ^ (key & 7)) << 3)) = kv;
    const int kc = key >> 3, ke = key & 7;
#pragma unroll
    for (int e = 0; e < 8; ++e) {
      int dim = ch * 8 + e;
      lVt[dim * 128 + ((kc ^ (dim & 7)) << 3) + ke] = vv[e];
    }
  }
  // ---- stage global K and V^T (32 keys at stride 64 tokens) ----
  {
    const int g = tid >> 3, ch = tid & 7;
    const int kpos = g * 64;
    ushortx8 kv = *(const ushortx8*)(Kb + (size_t)kpos * 256 + kvcol + ch * 8);
    ushortx8 vv = *(const ushortx8*)(Vb + (size_t)kpos * 256 + kvcol + ch * 8);
    *(ushortx8*)(lKg + g * 64 + ((ch ^ (g & 7)) << 3)) = kv;
#pragma unroll
    for (int e = 0; e < 8; ++e) lVtg[(ch * 8 + e) * 40 + g] = vv[e];
  }
  __syncthreads();

  const int lane = tid & 63, w = tid >> 6;
  const int quad = lane >> 4, l16 = lane & 15;
  const int l7 = l16 & 7;
  const float slope = exp2f(-0.5f * (float)(h + 1));

  // Q A-fragments straight from global: m = l16 (query), k = quad*8+e (dim)
  const int qrow = qb * 64 + w * 16 + l16;
  const ushort_t* qptr = Q + (size_t)qrow * 1024 + h * 64 + quad * 8;
  const bf16x8 aq0 = *(const bf16x8*)(qptr);
  const bf16x8 aq1 = *(const bf16x8*)(qptr + 32);

  // ---- local scores: S[q=quad*4+r][key=l16 within kt] ----
  float s[8][4];
#pragma unroll
  for (int kt = 0; kt < 8; ++kt) {
    const int key = kt * 16 + l16;
    const bf16x8 b0 = *(const bf16x8*)(lK + key * 64 + ((quad ^ l7) << 3));
    const bf16x8 b1 = *(const bf16x8*)(lK + key * 64 + (((4 + quad) ^ l7) << 3));
    f32x4 acc = {0.f, 0.f, 0.f, 0.f};
    acc = __builtin_amdgcn_mfma_f32_16x16x32_bf16(aq0, b0, acc, 0, 0, 0);
    acc = __builtin_amdgcn_mfma_f32_16x16x32_bf16(aq1, b1, acc, 0, 0, 0);
    const int kpos = kbase + key;
#pragma unroll
    for (int r = 0; r < 4; ++r) {
      const int qp = qb * 64 + w * 16 + quad * 4 + r;
      const int d = kpos - qp;
      const bool ok = (d <= 0) && (d >= -64) && (kpos >= 0);
      s[kt][r] = ok ? acc[r] * SCALE + (float)d * slope : -1e30f;
    }
  }
  float mr[4] = {-1e30f, -1e30f, -1e30f, -1e30f};
#pragma unroll
  for (int kt = 0; kt < 8; ++kt)
#pragma unroll
    for (int r = 0; r < 4; ++r) mr[r] = fmaxf(mr[r], s[kt][r]);
#pragma unroll
  for (int r = 0; r < 4; ++r) {
    mr[r] = fmaxf(mr[r], __shfl_xor(mr[r], 1));
    mr[r] = fmaxf(mr[r], __shfl_xor(mr[r], 2));
    mr[r] = fmaxf(mr[r], __shfl_xor(mr[r], 4));
    mr[r] = fmaxf(mr[r], __shfl_xor(mr[r], 8));
  }
  float lr[4] = {0.f, 0.f, 0.f, 0.f};
#pragma unroll
  for (int kt = 0; kt < 8; ++kt)
#pragma unroll
    for (int r = 0; r < 4; ++r) { float p = __expf(s[kt][r] - mr[r]); s[kt][r] = p; lr[r] += p; }
#pragma unroll
  for (int r = 0; r < 4; ++r) {
    lr[r] += __shfl_xor(lr[r], 1);
    lr[r] += __shfl_xor(lr[r], 2);
    lr[r] += __shfl_xor(lr[r], 4);
    lr[r] += __shfl_xor(lr[r], 8);
    lr[r] = 1.f / lr[r];
  }
#pragma unroll
  for (int kt = 0; kt < 8; ++kt) {
    const int kc = kt * 2 + (l16 >> 3);
#pragma unroll
    for (int r = 0; r < 4; ++r) {
      const int qr = w * 16 + quad * 4 + r;
      lP[qr * 128 + ((kc ^ (qr & 7)) << 3) + l7] = f2bf(s[kt][r] * lr[r]);
    }
  }

  // ---- global scores (no mask, no alibi, separate softmax) ----
  float sg[2][4];
#pragma unroll
  for (int g16 = 0; g16 < 2; ++g16) {
    const int key = g16 * 16 + l16;
    const bf16x8 b0 = *(const bf16x8*)(lKg + key * 64 + ((quad ^ l7) << 3));
    const bf16x8 b1 = *(const bf16x8*)(lKg + key * 64 + (((4 + quad) ^ l7) << 3));
    f32x4 acc = {0.f, 0.f, 0.f, 0.f};
    acc = __builtin_amdgcn_mfma_f32_16x16x32_bf16(aq0, b0, acc, 0, 0, 0);
    acc = __builtin_amdgcn_mfma_f32_16x16x32_bf16(aq1, b1, acc, 0, 0, 0);
#pragma unroll
    for (int r = 0; r < 4; ++r) sg[g16][r] = acc[r] * SCALE;
  }
  float mg[4], lg[4];
#pragma unroll
  for (int r = 0; r < 4; ++r) {
    mg[r] = fmaxf(sg[0][r], sg[1][r]);
    mg[r] = fmaxf(mg[r], __shfl_xor(mg[r], 1));
    mg[r] = fmaxf(mg[r], __shfl_xor(mg[r], 2));
    mg[r] = fmaxf(mg[r], __shfl_xor(mg[r], 4));
    mg[r] = fmaxf(mg[r], __shfl_xor(mg[r], 8));
  }
#pragma unroll
  for (int r = 0; r < 4; ++r) {
    float p0 = __expf(sg[0][r] - mg[r]);
    float p1 = __expf(sg[1][r] - mg[r]);
    sg[0][r] = p0; sg[1][r] = p1;
    lg[r] = p0 + p1;
    lg[r] += __shfl_xor(lg[r], 1);
    lg[r] += __shfl_xor(lg[r], 2);
    lg[r] += __shfl_xor(lg[r], 4);
    lg[r] += __shfl_xor(lg[r], 8);
    lg[r] = 1.f / lg[r];
  }
#pragma unroll
  for (int g16 = 0; g16 < 2; ++g16)
#pragma unroll
    for (int r = 0; r < 4; ++r) {
      const int qr = w * 16 + quad * 4 + r;
      lPg[qr * 40 + g16 * 16 + l16] = f2bf(sg[g16][r] * lg[r]);
    }

  // ---- PV (wave-private P rows: same-wave DS ops are in order; no barrier) ----
  f32x4 acco[4] = {};
  const int qA = w * 16 + l16;
#pragma unroll
  for (int kki = 0; kki < 4; ++kki) {
    const bf16x8 ap = *(const bf16x8*)(lP + qA * 128 + (((kki * 4 + quad) ^ l7) << 3));
#pragma unroll
    for (int nt = 0; nt < 4; ++nt) {
      const int dim = nt * 16 + l16;
      const bf16x8 bv = *(const bf16x8*)(lVt + dim * 128 + (((kki * 4 + quad) ^ l7) << 3));
      acco[nt] = __builtin_amdgcn_mfma_f32_16x16x32_bf16(ap, bv, acco[nt], 0, 0, 0);
    }
  }
  {
    const bf16x8 apg = *(const bf16x8*)(lPg + qA * 40 + quad * 8);
#pragma unroll
    for (int nt = 0; nt < 4; ++nt) {
      const bf16x8 bvg = *(const bf16x8*)(lVtg + (nt * 16 + l16) * 40 + quad * 8);
      acco[nt] = __builtin_amdgcn_mfma_f32_16x16x32_bf16(apg, bvg, acco[nt], 0, 0, 0);
    }
  }
#pragma unroll
  for (int nt = 0; nt < 4; ++nt)
#pragma unroll
    for (int r = 0; r < 4; ++r) {
      const int qp = qb * 64 + w * 16 + quad * 4 + r;
      O[(size_t)qp * 1024 + h * 64 + nt * 16 + l16] = f2bf(acco[nt][r]);
    }
}

// ---------------- output GEMM: C[2048][1024] = A[2048][1024] * Bt[1024][1024]^T, 128x64 tiles ----------------
__global__ __launch_bounds__(256) void gemm_out_kernel(
    const ushort_t* __restrict__ A, const ushort_t* __restrict__ Bt, float* __restrict__ fout)
{
  __shared__ __align__(16) ushort_t lA[128 * 32];
  __shared__ __align__(16) ushort_t lB[64 * 32];
  const int tid = threadIdx.x;
  const int lane = tid & 63, wid = tid >> 6;
  const int quad = lane >> 4, l16 = lane & 15;
  const int m0 = blockIdx.y * 128, n0 = blockIdx.x * 64;
  const int e0 = tid * 8, r0 = e0 >> 5, c0 = e0 & 31;
  const int e1 = e0 + 2048, r1 = e1 >> 5, c1 = e1 & 31;
  const ushort_t* Ab = A + (size_t)m0 * 1024;
  const ushort_t* Bb = Bt + (size_t)n0 * 1024;

  f32x4 acc[2][4] = {};

  for (int k0 = 0; k0 < 1024; k0 += 32) {
    __syncthreads();
    __builtin_amdgcn_global_load_lds(
        (const __attribute__((address_space(1))) unsigned int*)(Ab + (size_t)r0 * 1024 + k0 + c0),
        (__attribute__((address_space(3))) unsigned int*)(lA + e0), 16, 0, 0);
    __builtin_amdgcn_global_load_lds(
        (const __attribute__((address_space(1))) unsigned int*)(Ab + (size_t)r1 * 1024 + k0 + c1),
        (__attribute__((address_space(3))) unsigned int*)(lA + e1), 16, 0, 0);
    __builtin_amdgcn_global_load_lds(
        (const __attribute__((address_space(1))) unsigned int*)(Bb + (size_t)r0 * 1024 + k0 + c0),
        (__attribute__((address_space(3))) unsigned int*)(lB + e0), 16, 0, 0);
    __syncthreads();

    bf16x8 bfr[4];
#pragma unroll
    for (int ni = 0; ni < 4; ++ni)
      bfr[ni] = *(const bf16x8*)(lB + (ni * 16 + l16) * 32 + quad * 8);
#pragma unroll
    for (int mi = 0; mi < 2; ++mi) {
      bf16x8 afr = *(const bf16x8*)(lA + (wid * 32 + mi * 16 + l16) * 32 + quad * 8);
#pragma unroll
      for (int ni = 0; ni < 4; ++ni)
        acc[mi][ni] = __builtin_amdgcn_mfma_f32_16x16x32_bf16(afr, bfr[ni], acc[mi][ni], 0, 0, 0);
    }
  }

#pragma unroll
  for (int mi = 0; mi < 2; ++mi)
#pragma unroll
    for (int ni = 0; ni < 4; ++ni)
#pragma unroll
      for (int r = 0; r < 4; ++r) {
        int row = m0 + wid * 32 + mi * 16 + quad * 4 + r;
        int col = n0 + ni * 16 + l16;
        fout[(size_t)row * 1024 + col] = acc[mi][ni][r];
      }
}

extern "C" void kernel_launch(void* const* d_in, const int* in_sizes, int n_in,
                              void* d_out, int out_size, void* d_ws, size_t ws_size,
                              hipStream_t stream)
{
  const float* x  = (const float*)d_in[0];
  const float* Wq = (const float*)d_in[1];
  const float* Wk = (const float*)d_in[2];
  const float* Wv = (const float*)d_in[3];
  const float* Wo = (const float*)d_in[4];
  float* out = (float*)d_out;

  char* ws = (char*)d_ws;
  ushort_t* x_bf   = (ushort_t*)(ws);                        // 4 MB   [2048][1024]
  ushort_t* wqkv_t = (ushort_t*)(ws + (4ull  << 20));        // 3 MB   [1536][1024]
  ushort_t* wo_t   = (ushort_t*)(ws + (7ull  << 20));        // 2 MB   [1024][1024]
  ushort_t* q_bf   = (ushort_t*)(ws + (9ull  << 20));        // 4 MB   [2048][1024]
  ushort_t* k_bf   = (ushort_t*)(ws + (13ull << 20));        // 1 MB   [2048][256]
  ushort_t* v_bf   = (ushort_t*)(ws + (14ull << 20));        // 1 MB   [2048][256]
  ushort_t* at_bf  = (ushort_t*)(ws + (15ull << 20));        // 4 MB   [2048][1024]

  prep_kernel<<<2688, 256, 0, stream>>>(x, Wq, Wk, Wv, Wo, x_bf, wqkv_t, wo_t);
  gemm_qkv_kernel<<<dim3(12, 16), 256, 0, stream>>>(x_bf, wqkv_t, q_bf, k_bf, v_bf);
  attn_mfma_kernel<<<dim3(16, 32), 256, 0, stream>>>(q_bf, k_bf, v_bf, at_bf);
  gemm_out_kernel<<<dim3(16, 16), 256, 0, stream>>>(at_bf, wo_t, out);
}

// Round 3
// 109.929 us; speedup vs baseline: 1.5286x; 1.1429x over previous
//
#include <hip/hip_runtime.h>

#define SCALE 0.125f

typedef unsigned short ushort_t;
typedef unsigned short ushortx8 __attribute__((ext_vector_type(8)));
typedef unsigned short ushortx4 __attribute__((ext_vector_type(4)));
typedef short bf16x8 __attribute__((ext_vector_type(8)));
typedef float f32x4 __attribute__((ext_vector_type(4)));

__device__ inline ushort_t f2bf(float f) {
  unsigned int u = __float_as_uint(f);
  u += 0x7FFFu + ((u >> 16) & 1u);
  return (ushort_t)(u >> 16);
}
__device__ inline float bf2f(ushort_t u) {
  return __uint_as_float(((unsigned int)u) << 16);
}

// ---------------- fused prep: x cvt + 4 weight transposes ----------------
__global__ __launch_bounds__(256) void prep_kernel(
    const float* __restrict__ x, const float* __restrict__ Wq, const float* __restrict__ Wk,
    const float* __restrict__ Wv, const float* __restrict__ Wo,
    ushort_t* __restrict__ x_bf, ushort_t* __restrict__ wqkv_t, ushort_t* __restrict__ wo_t)
{
  __shared__ float t[64][65];
  int bid = blockIdx.x;
  const int tid = threadIdx.x;
  if (bid < 2048) {
    int idx = (bid * 256 + tid) * 4;
    if (idx < 2048 * 1024) {
      float4 f = *(const float4*)(x + idx);
      ushortx4 o = { f2bf(f.x), f2bf(f.y), f2bf(f.z), f2bf(f.w) };
      *(ushortx4*)(x_bf + idx) = o;
    }
    return;
  }
  bid -= 2048;
  const float* src; int C; ushort_t* dst; int row_off, cb, kb;
  if (bid < 256)      { src = Wq; C = 1024; dst = wqkv_t; row_off = 0;    cb = bid & 15; kb = bid >> 4; }
  else if (bid < 320) { int j = bid - 256; src = Wk; C = 256; dst = wqkv_t; row_off = 1024; cb = j & 3; kb = j >> 2; }
  else if (bid < 384) { int j = bid - 320; src = Wv; C = 256; dst = wqkv_t; row_off = 1280; cb = j & 3; kb = j >> 2; }
  else                { int j = bid - 384; src = Wo; C = 1024; dst = wo_t; row_off = 0;    cb = j & 15; kb = j >> 4; }
  const int c0 = cb * 64, k0 = kb * 64;
  const int c = tid & 63, r4 = tid >> 6;
  for (int rr = r4; rr < 64; rr += 4)
    t[c][rr] = src[(size_t)(k0 + rr) * C + c0 + c];
  __syncthreads();
  const int kk = tid & 63, n4 = tid >> 6;
  for (int nn = n4; nn < 64; nn += 4)
    dst[(size_t)(row_off + c0 + nn) * 1024 + k0 + kk] = f2bf(t[nn][kk]);
}

// ---------------- 64x64-tile BK=64 GEMM, xor-swizzled LDS, XCD-aware 1-D grid ----------------
// C[M][N] = A[M][1024] * Bt[N][1024]^T.  bid = g*8 + xcd; m_tile = xcd + 8*(g/ntn); n_tile = g%ntn.
// mode 0: split bf16 out to q/k/v. mode 1: fp32 out [.][1024].
__global__ __launch_bounds__(256) void gemm64_kernel(
    const ushort_t* __restrict__ A, const ushort_t* __restrict__ Bt, int mode, int ntn,
    ushort_t* __restrict__ qout, ushort_t* __restrict__ kout, ushort_t* __restrict__ vout,
    float* __restrict__ fout)
{
  __shared__ __align__(16) ushort_t lA[64 * 64];
  __shared__ __align__(16) ushort_t lB[64 * 64];
  const int bid = blockIdx.x;
  const int xcd = bid & 7, g = bid >> 3;
  const int m0 = (xcd + 8 * (g / ntn)) * 64;
  const int n0 = (g % ntn) * 64;

  const int tid = threadIdx.x;
  const int lane = tid & 63, w = tid >> 6;
  const int quad = lane >> 4, l16 = lane & 15;
  const int rw = (w >> 1) * 32, cw = (w & 1) * 32;

  // staging: 2 chunk-loads per array; LDS(row, pos) holds global chunk (pos ^ (row&7))
  const int rs = tid >> 3;                         // 0..31
  const int swz = (tid & 7) ^ (rs & 7);            // global chunk to fetch
  const int eL = tid * 8;                          // LDS elem offset, load j adds j*2048
  const ushort_t* Ab = A + (size_t)(m0 + rs) * 1024 + swz * 8;
  const ushort_t* Bb = Bt + (size_t)(n0 + rs) * 1024 + swz * 8;

  const int xa = l16 & 7;                          // row&7 for frag rows
  f32x4 acc[2][2] = {};

  for (int k0 = 0; k0 < 1024; k0 += 64) {
    __syncthreads();
    __builtin_amdgcn_global_load_lds(
        (const __attribute__((address_space(1))) unsigned int*)(Ab + k0),
        (__attribute__((address_space(3))) unsigned int*)(lA + eL), 16, 0, 0);
    __builtin_amdgcn_global_load_lds(
        (const __attribute__((address_space(1))) unsigned int*)(Ab + 32 * 1024 + k0),
        (__attribute__((address_space(3))) unsigned int*)(lA + eL + 2048), 16, 0, 0);
    __builtin_amdgcn_global_load_lds(
        (const __attribute__((address_space(1))) unsigned int*)(Bb + k0),
        (__attribute__((address_space(3))) unsigned int*)(lB + eL), 16, 0, 0);
    __builtin_amdgcn_global_load_lds(
        (const __attribute__((address_space(1))) unsigned int*)(Bb + 32 * 1024 + k0),
        (__attribute__((address_space(3))) unsigned int*)(lB + eL + 2048), 16, 0, 0);
    __syncthreads();

#pragma unroll
    for (int kh = 0; kh < 2; ++kh) {
      bf16x8 a0 = *(const bf16x8*)(lA + (rw + l16) * 64      + (((kh * 4 + quad) ^ xa) << 3));
      bf16x8 a1 = *(const bf16x8*)(lA + (rw + 16 + l16) * 64 + (((kh * 4 + quad) ^ xa) << 3));
      bf16x8 b0 = *(const bf16x8*)(lB + (cw + l16) * 64      + (((kh * 4 + quad) ^ xa) << 3));
      bf16x8 b1 = *(const bf16x8*)(lB + (cw + 16 + l16) * 64 + (((kh * 4 + quad) ^ xa) << 3));
      acc[0][0] = __builtin_amdgcn_mfma_f32_16x16x32_bf16(a0, b0, acc[0][0], 0, 0, 0);
      acc[0][1] = __builtin_amdgcn_mfma_f32_16x16x32_bf16(a0, b1, acc[0][1], 0, 0, 0);
      acc[1][0] = __builtin_amdgcn_mfma_f32_16x16x32_bf16(a1, b0, acc[1][0], 0, 0, 0);
      acc[1][1] = __builtin_amdgcn_mfma_f32_16x16x32_bf16(a1, b1, acc[1][1], 0, 0, 0);
    }
  }

#pragma unroll
  for (int mg = 0; mg < 2; ++mg)
#pragma unroll
    for (int ng = 0; ng < 2; ++ng)
#pragma unroll
      for (int r = 0; r < 4; ++r) {
        const int row = m0 + rw + mg * 16 + quad * 4 + r;
        const int col = n0 + cw + ng * 16 + l16;
        const float v = acc[mg][ng][r];
        if (mode == 0) {
          if (n0 < 1024)       qout[(size_t)row * 1024 + col] = f2bf(v);
          else if (n0 < 1280)  kout[(size_t)row * 256 + (col - 1024)] = f2bf(v);
          else                 vout[(size_t)row * 256 + (col - 1280)] = f2bf(v);
        } else {
          fout[(size_t)row * 1024 + col] = v;
        }
      }
}

// ---------------- MFMA attention: block = (head, 64-query tile) ----------------
__global__ __launch_bounds__(256) void attn_mfma_kernel(
    const ushort_t* __restrict__ Q, const ushort_t* __restrict__ Kb,
    const ushort_t* __restrict__ Vb, ushort_t* __restrict__ O)
{
  __shared__ __align__(16) ushort_t lK[128 * 64];
  __shared__ __align__(16) ushort_t lVt[64 * 128];
  __shared__ __align__(16) ushort_t lKg[32 * 64];
  __shared__ __align__(16) ushort_t lVtg[64 * 40];
  __shared__ __align__(16) ushort_t lP[64 * 128];
  __shared__ __align__(16) ushort_t lPg[64 * 40];

  const int h = blockIdx.x, qb = blockIdx.y;
  const int tid = threadIdx.x;
  const int kvcol = (h >> 2) * 64;
  const int kbase = qb * 64 - 64;

  for (int cidx = tid; cidx < 1024; cidx += 256) {
    const int key = cidx >> 3, ch = cidx & 7;
    const int kpos = kbase + key;
    ushortx8 kv = {0,0,0,0,0,0,0,0}, vv = {0,0,0,0,0,0,0,0};
    if (kpos >= 0) {
      kv = *(const ushortx8*)(Kb + (size_t)kpos * 256 + kvcol + ch * 8);
      vv = *(const ushortx8*)(Vb + (size_t)kpos * 256 + kvcol + ch * 8);
    }
    *(ushortx8*)(lK + key * 64 + ((ch ^ (key & 7)) << 3)) = kv;
    const int kc = key >> 3, ke = key & 7;
#pragma unroll
    for (int e = 0; e < 8; ++e) {
      int dim = ch * 8 + e;
      lVt[dim * 128 + ((kc ^ (dim & 7)) << 3) + ke] = vv[e];
    }
  }
  {
    const int gk = tid >> 3, ch = tid & 7;
    const int kpos = gk * 64;
    ushortx8 kv = *(const ushortx8*)(Kb + (size_t)kpos * 256 + kvcol + ch * 8);
    ushortx8 vv = *(const ushortx8*)(Vb + (size_t)kpos * 256 + kvcol + ch * 8);
    *(ushortx8*)(lKg + gk * 64 + ((ch ^ (gk & 7)) << 3)) = kv;
#pragma unroll
    for (int e = 0; e < 8; ++e) lVtg[(ch * 8 + e) * 40 + gk] = vv[e];
  }
  __syncthreads();

  const int lane = tid & 63, w = tid >> 6;
  const int quad = lane >> 4, l16 = lane & 15;
  const int l7 = l16 & 7;
  const float slope = exp2f(-0.5f * (float)(h + 1));

  const int qrow = qb * 64 + w * 16 + l16;
  const ushort_t* qptr = Q + (size_t)qrow * 1024 + h * 64 + quad * 8;
  const bf16x8 aq0 = *(const bf16x8*)(qptr);
  const bf16x8 aq1 = *(const bf16x8*)(qptr + 32);

  float s[8][4];
#pragma unroll
  for (int kt = 0; kt < 8; ++kt) {
    const int key = kt * 16 + l16;
    const bf16x8 b0 = *(const bf16x8*)(lK + key * 64 + ((quad ^ l7) << 3));
    const bf16x8 b1 = *(const bf16x8*)(lK + key * 64 + (((4 + quad) ^ l7) << 3));
    f32x4 acc = {0.f, 0.f, 0.f, 0.f};
    acc = __builtin_amdgcn_mfma_f32_16x16x32_bf16(aq0, b0, acc, 0, 0, 0);
    acc = __builtin_amdgcn_mfma_f32_16x16x32_bf16(aq1, b1, acc, 0, 0, 0);
    const int kpos = kbase + key;
#pragma unroll
    for (int r = 0; r < 4; ++r) {
      const int qp = qb * 64 + w * 16 + quad * 4 + r;
      const int d = kpos - qp;
      const bool ok = (d <= 0) && (d >= -64) && (kpos >= 0);
      s[kt][r] = ok ? acc[r] * SCALE + (float)d * slope : -1e30f;
    }
  }
  float mr[4] = {-1e30f, -1e30f, -1e30f, -1e30f};
#pragma unroll
  for (int kt = 0; kt < 8; ++kt)
#pragma unroll
    for (int r = 0; r < 4; ++r) mr[r] = fmaxf(mr[r], s[kt][r]);
#pragma unroll
  for (int r = 0; r < 4; ++r) {
    mr[r] = fmaxf(mr[r], __shfl_xor(mr[r], 1));
    mr[r] = fmaxf(mr[r], __shfl_xor(mr[r], 2));
    mr[r] = fmaxf(mr[r], __shfl_xor(mr[r], 4));
    mr[r] = fmaxf(mr[r], __shfl_xor(mr[r], 8));
  }
  float lr[4] = {0.f, 0.f, 0.f, 0.f};
#pragma unroll
  for (int kt = 0; kt < 8; ++kt)
#pragma unroll
    for (int r = 0; r < 4; ++r) { float p = __expf(s[kt][r] - mr[r]); s[kt][r] = p; lr[r] += p; }
#pragma unroll
  for (int r = 0; r < 4; ++r) {
    lr[r] += __shfl_xor(lr[r], 1);
    lr[r] += __shfl_xor(lr[r], 2);
    lr[r] += __shfl_xor(lr[r], 4);
    lr[r] += __shfl_xor(lr[r], 8);
    lr[r] = 1.f / lr[r];
  }
#pragma unroll
  for (int kt = 0; kt < 8; ++kt) {
    const int kc = kt * 2 + (l16 >> 3);
#pragma unroll
    for (int r = 0; r < 4; ++r) {
      const int qr = w * 16 + quad * 4 + r;
      lP[qr * 128 + ((kc ^ (qr & 7)) << 3) + l7] = f2bf(s[kt][r] * lr[r]);
    }
  }

  float sg[2][4];
#pragma unroll
  for (int g16 = 0; g16 < 2; ++g16) {
    const int key = g16 * 16 + l16;
    const bf16x8 b0 = *(const bf16x8*)(lKg + key * 64 + ((quad ^ l7) << 3));
    const bf16x8 b1 = *(const bf16x8*)(lKg + key * 64 + (((4 + quad) ^ l7) << 3));
    f32x4 acc = {0.f, 0.f, 0.f, 0.f};
    acc = __builtin_amdgcn_mfma_f32_16x16x32_bf16(aq0, b0, acc, 0, 0, 0);
    acc = __builtin_amdgcn_mfma_f32_16x16x32_bf16(aq1, b1, acc, 0, 0, 0);
#pragma unroll
    for (int r = 0; r < 4; ++r) sg[g16][r] = acc[r] * SCALE;
  }
  float mg[4], lg[4];
#pragma unroll
  for (int r = 0; r < 4; ++r) {
    mg[r] = fmaxf(sg[0][r], sg[1][r]);
    mg[r] = fmaxf(mg[r], __shfl_xor(mg[r], 1));
    mg[r] = fmaxf(mg[r], __shfl_xor(mg[r], 2));
    mg[r] = fmaxf(mg[r], __shfl_xor(mg[r], 4));
    mg[r] = fmaxf(mg[r], __shfl_xor(mg[r], 8));
  }
#pragma unroll
  for (int r = 0; r < 4; ++r) {
    float p0 = __expf(sg[0][r] - mg[r]);
    float p1 = __expf(sg[1][r] - mg[r]);
    sg[0][r] = p0; sg[1][r] = p1;
    lg[r] = p0 + p1;
    lg[r] += __shfl_xor(lg[r], 1);
    lg[r] += __shfl_xor(lg[r], 2);
    lg[r] += __shfl_xor(lg[r], 4);
    lg[r] += __shfl_xor(lg[r], 8);
    lg[r] = 1.f / lg[r];
  }
#pragma unroll
  for (int g16 = 0; g16 < 2; ++g16)
#pragma unroll
    for (int r = 0; r < 4; ++r) {
      const int qr = w * 16 + quad * 4 + r;
      lPg[qr * 40 + g16 * 16 + l16] = f2bf(sg[g16][r] * lg[r]);
    }

  f32x4 acco[4] = {};
  const int qA = w * 16 + l16;
#pragma unroll
  for (int kki = 0; kki < 4; ++kki) {
    const bf16x8 ap = *(const bf16x8*)(lP + qA * 128 + (((kki * 4 + quad) ^ l7) << 3));
#pragma unroll
    for (int nt = 0; nt < 4; ++nt) {
      const int dim = nt * 16 + l16;
      const bf16x8 bv = *(const bf16x8*)(lVt + dim * 128 + (((kki * 4 + quad) ^ l7) << 3));
      acco[nt] = __builtin_amdgcn_mfma_f32_16x16x32_bf16(ap, bv, acco[nt], 0, 0, 0);
    }
  }
  {
    const bf16x8 apg = *(const bf16x8*)(lPg + qA * 40 + quad * 8);
#pragma unroll
    for (int nt = 0; nt < 4; ++nt) {
      const bf16x8 bvg = *(const bf16x8*)(lVtg + (nt * 16 + l16) * 40 + quad * 8);
      acco[nt] = __builtin_amdgcn_mfma_f32_16x16x32_bf16(apg, bvg, acco[nt], 0, 0, 0);
    }
  }
#pragma unroll
  for (int nt = 0; nt < 4; ++nt)
#pragma unroll
    for (int r = 0; r < 4; ++r) {
      const int qp = qb * 64 + w * 16 + quad * 4 + r;
      O[(size_t)qp * 1024 + h * 64 + nt * 16 + l16] = f2bf(acco[nt][r]);
    }
}

extern "C" void kernel_launch(void* const* d_in, const int* in_sizes, int n_in,
                              void* d_out, int out_size, void* d_ws, size_t ws_size,
                              hipStream_t stream)
{
  const float* x  = (const float*)d_in[0];
  const float* Wq = (const float*)d_in[1];
  const float* Wk = (const float*)d_in[2];
  const float* Wv = (const float*)d_in[3];
  const float* Wo = (const float*)d_in[4];
  float* out = (float*)d_out;

  char* ws = (char*)d_ws;
  ushort_t* x_bf   = (ushort_t*)(ws);                        // 4 MB   [2048][1024]
  ushort_t* wqkv_t = (ushort_t*)(ws + (4ull  << 20));        // 3 MB   [1536][1024]
  ushort_t* wo_t   = (ushort_t*)(ws + (7ull  << 20));        // 2 MB   [1024][1024]
  ushort_t* q_bf   = (ushort_t*)(ws + (9ull  << 20));        // 4 MB   [2048][1024]
  ushort_t* k_bf   = (ushort_t*)(ws + (13ull << 20));        // 1 MB   [2048][256]
  ushort_t* v_bf   = (ushort_t*)(ws + (14ull << 20));        // 1 MB   [2048][256]
  ushort_t* at_bf  = (ushort_t*)(ws + (15ull << 20));        // 4 MB   [2048][1024]

  prep_kernel<<<2688, 256, 0, stream>>>(x, Wq, Wk, Wv, Wo, x_bf, wqkv_t, wo_t);
  gemm64_kernel<<<768, 256, 0, stream>>>(x_bf, wqkv_t, 0, 24, q_bf, k_bf, v_bf, nullptr);
  attn_mfma_kernel<<<dim3(16, 32), 256, 0, stream>>>(q_bf, k_bf, v_bf, at_bf);
  gemm64_kernel<<<512, 256, 0, stream>>>(at_bf, wo_t, 1, 16, nullptr, nullptr, nullptr, out);
}